// Round 2
// baseline (241.329 us; speedup 1.0000x reference)
//
#include <hip/hip_runtime.h>
#include <hip/hip_bf16.h>

typedef unsigned short u16;
typedef unsigned int u32;

// ---------------------------------------------------------------------------
// Kernel A: per-node precompute. One thread = one node, computes ALL 128
// outputs (P then Q) from a single z-row read. z fetched exactly once
// (25.6 MB total). W1 accesses are wave-uniform -> scalar (K$) loads, so the
// inner loop is pure v_fmac_f32 at ~2 cyc each.
//   P[n][h] = b1[h] + sum_k z[n][k] * W1[k][h]        (phase 0)
//   Q[n][h] =         sum_k z[n][k] * W1[64+k][h]     (phase 1)
// Stored bf16: pq[n][0:64] = P, pq[n][64:128] = Q  (row = 256 B).
// ---------------------------------------------------------------------------
__global__ __launch_bounds__(256) void node_precompute(
    const float* __restrict__ z, const float* __restrict__ W1,
    const float* __restrict__ b1, u16* __restrict__ pq, int nNodes)
{
    const int n = blockIdx.x * 256 + threadIdx.x;
    if (n >= nNodes) return;

    // z row -> 64 VGPRs (coalesced float4 loads)
    float zr[64];
    const float4* z4 = (const float4*)(z + (size_t)n * 64);
#pragma unroll
    for (int i = 0; i < 16; ++i) {
        float4 v = z4[i];
        zr[4*i+0] = v.x; zr[4*i+1] = v.y; zr[4*i+2] = v.z; zr[4*i+3] = v.w;
    }

    u16* orow = pq + (size_t)n * 128;

#pragma unroll 1
    for (int ph = 0; ph < 2; ++ph) {
        const float* wb = W1 + (size_t)ph * 64 * 64;   // top / bottom half of W1
        float acc[64];
#pragma unroll
        for (int h = 0; h < 64; ++h) acc[h] = ph ? 0.0f : b1[h];

#pragma unroll 1
        for (int k = 0; k < 64; ++k) {
            const float zk = zr[k];
            const float* wr = wb + (size_t)k * 64;     // wave-uniform -> s_load
#pragma unroll
            for (int h = 0; h < 64; ++h)
                acc[h] = fmaf(zk, wr[h], acc[h]);
        }

        // pack to bf16 (RNE) and store 128 B
        u16 ob[64];
#pragma unroll
        for (int h = 0; h < 64; ++h) {
            __hip_bfloat16 b = __float2bfloat16(acc[h]);
            ob[h] = *(u16*)&b;
        }
        uint4* dst = (uint4*)(orow + ph * 64);
#pragma unroll
        for (int t = 0; t < 8; ++t) dst[t] = ((const uint4*)ob)[t];
    }
}

// ---------------------------------------------------------------------------
// Kernel B: wave-cooperative edge gather + MLP tail.
//   out[e] = b2 + sum_h W2[h] * relu(P[i][h] + Q[j][h])
// One edge per wave-iteration: lanes 0-31 load the 128 B P_i row, lanes
// 32-63 the 128 B Q_j row in a SINGLE global_load_dword (4 cache-line
// requests/edge). Halves swap via shfl_xor(32); both halves then hold
// identical (p,q) pairs, 5-step xor-reduce within each 32-half gives the
// full 64-term dot. Edge t's result is kept in lane t; one coalesced
// store per 64-edge batch.
// ---------------------------------------------------------------------------
__global__ __launch_bounds__(256) void edge_mlp(
    const int* __restrict__ e0, const int* __restrict__ e1,
    const u16* __restrict__ pq, const float* __restrict__ W2,
    const float* __restrict__ b2, float* __restrict__ out, int E)
{
    const int lane  = threadIdx.x & 63;
    const int wave  = (blockIdx.x * 256 + threadIdx.x) >> 6;
    const int nWave = (gridDim.x * 256) >> 6;

    const int hl  = lane & 31;        // h-pair index this lane handles
    const int isQ = lane >> 5;        // 0: load P_i, 1: load Q_j
    const float w2a = W2[2*hl];
    const float w2b = W2[2*hl+1];
    const float bias = b2[0];

    for (int base = wave * 64; base < E; base += nWave * 64) {
        // lane l holds indices of edge base+l
        int vi = 0, vj = 0;
        if (base + lane < E) { vi = e0[base + lane]; vj = e1[base + lane]; }

        float res = 0.0f;
#pragma unroll
        for (int t = 0; t < 64; ++t) {
            const int i = __shfl(vi, t);          // broadcast -> scalar
            const int j = __shfl(vj, t);
            const int node = isQ ? j : i;
            const u32 w = ((const u32*)(pq + (size_t)node * 128 + isQ * 64))[hl];
            const u32 wq = __shfl_xor(w, 32);     // partner half's word

            const float p0 = __uint_as_float(w << 16);
            const float p1 = __uint_as_float(w & 0xffff0000u);
            const float q0 = __uint_as_float(wq << 16);
            const float q1 = __uint_as_float(wq & 0xffff0000u);
            const float a0 = fmaxf(p0 + q0, 0.0f);
            const float a1 = fmaxf(p1 + q1, 0.0f);
            float part = fmaf(a1, w2b, a0 * w2a);

            part += __shfl_xor(part, 1);
            part += __shfl_xor(part, 2);
            part += __shfl_xor(part, 4);
            part += __shfl_xor(part, 8);
            part += __shfl_xor(part, 16);

            res = (lane == t) ? part + bias : res;
        }
        if (base + lane < E) out[base + lane] = res;
    }
}

// ---------------------------------------------------------------------------
extern "C" void kernel_launch(void* const* d_in, const int* in_sizes, int n_in,
                              void* d_out, int out_size, void* d_ws, size_t ws_size,
                              hipStream_t stream) {
    const float* z  = (const float*)d_in[0];
    const int*   eg = (const int*)d_in[1];
    const float* W1 = (const float*)d_in[2];
    const float* b1 = (const float*)d_in[3];
    const float* W2 = (const float*)d_in[4];
    const float* b2 = (const float*)d_in[5];
    float* out = (float*)d_out;

    const int nNodes = in_sizes[0] / 64;   // 100000
    const int E      = in_sizes[1] / 2;    // 1000000

    u16* pq = (u16*)d_ws;                  // nNodes*128*2 = 25.6 MB

    dim3 gA((nNodes + 255) / 256);
    node_precompute<<<gA, dim3(256), 0, stream>>>(z, W1, b1, pq, nNodes);

    // 4 waves/block * 64 edges/wave = 256 edges per block
    dim3 gB((E + 255) / 256);
    edge_mlp<<<gB, dim3(256), 0, stream>>>(eg, eg + E, pq, W2, b2, out, E);
}

// Round 3
// 216.414 us; speedup vs baseline: 1.1151x; 1.1151x over previous
//
#include <hip/hip_runtime.h>
#include <hip/hip_bf16.h>

typedef unsigned short u16;
typedef unsigned int u32;

// ---------------------------------------------------------------------------
// Kernel A: per-node precompute.
//   P[n][h] = b1[h] + sum_k z[n][k] * W1[k][h]
//   Q[n][h] =         sum_k z[n][k] * W1[64+k][h]
// Stored bf16: pq[n][0:64] = P, pq[n][64:128] = Q  (row = 256 B).
//
// Block = 256 threads = 64 nodes x 4 quarter-threads. Quarter q = tid>>6
// (wave-uniform) computes output columns q*32..q*32+31 of the 128-wide
// concat [P|Q]. z rows staged TRANSPOSED in LDS (stride 65 -> only 2-way
// bank aliasing, which is free), so z is fetched from HBM exactly once,
// coalesced. acc[32] keeps VGPR ~60 -> no spills, high occupancy. W1 row
// addresses are wave-uniform -> scalar / broadcast loads.
// ---------------------------------------------------------------------------
__global__ __launch_bounds__(256) void node_precompute(
    const float* __restrict__ z, const float* __restrict__ W1,
    const float* __restrict__ b1, u16* __restrict__ pq, int nNodes)
{
    __shared__ float zT[64 * 65];            // zT[k][node], padded stride 65
    const int tid  = threadIdx.x;
    const int nb   = blockIdx.x * 64;        // first node of this block
    const int node = tid & 63;
    const int q    = tid >> 6;               // 0..3, wave-uniform

    // ---- stage z[nb..nb+63][0:64] transposed into LDS ----
    const int nNode = (nNodes - nb >= 64) ? 64 : (nNodes - nb);
    const int maxf  = nNode * 16;            // float4 count
    const float4* zg = (const float4*)(z + (size_t)nb * 64);
    for (int f = tid; f < maxf; f += 256) {
        float4 v = zg[f];
        int n4 = f >> 4, kb = (f & 15) * 4;
        zT[(kb + 0) * 65 + n4] = v.x;
        zT[(kb + 1) * 65 + n4] = v.y;
        zT[(kb + 2) * 65 + n4] = v.z;
        zT[(kb + 3) * 65 + n4] = v.w;
    }
    __syncthreads();

    if (nb + node >= nNodes) return;

    // quarter q: cols (q&1)*32..+31 of P-half (q<2) or Q-half (q>=2)
    const float* wb = W1 + (size_t)(q >> 1) * 64 * 64 + (q & 1) * 32;

    float acc[32];
#pragma unroll
    for (int h = 0; h < 32; ++h)
        acc[h] = (q < 2) ? b1[(q & 1) * 32 + h] : 0.0f;

#pragma unroll 2
    for (int k = 0; k < 64; ++k) {
        const float zk = zT[k * 65 + node];
        const float* wr = wb + (size_t)k * 64;   // wave-uniform
#pragma unroll
        for (int h = 0; h < 32; ++h)
            acc[h] = fmaf(zk, wr[h], acc[h]);
    }

    // pack 32 results to bf16, store 64 B
    u16 ob[32];
#pragma unroll
    for (int h = 0; h < 32; ++h) {
        __hip_bfloat16 b = __float2bfloat16(acc[h]);
        ob[h] = *(u16*)&b;
    }
    uint4* dst = (uint4*)(pq + (size_t)(nb + node) * 128 + q * 32);
#pragma unroll
    for (int t = 0; t < 4; ++t) dst[t] = ((const uint4*)ob)[t];
}

// ---------------------------------------------------------------------------
// Kernel B: edge MLP tail, 8 lanes per edge.
//   out[e] = b2 + sum_h W2[h] * relu(P[i][h] + Q[j][h])
// Lane sub = gid&7 loads uint4 #sub of the P_i row and of the Q_j row:
// per 8-lane group the addresses are contiguous (128 B row = 2 cache
// lines), so one wave gather instruction costs 16 line-requests for 8
// edges -> 4 lines/edge total (vs 16 for thread-per-edge). No index
// broadcasts needed (each lane loads its group's indices, coalesced).
// 8-term partial dot per lane, 3-step shfl_xor reduce, lane sub==0 stores.
// ---------------------------------------------------------------------------
__global__ __launch_bounds__(256) void edge_mlp(
    const int* __restrict__ e0, const int* __restrict__ e1,
    const u16* __restrict__ pq, const float* __restrict__ W2,
    const float* __restrict__ b2, float* __restrict__ out, int E)
{
    const int gid = blockIdx.x * 256 + threadIdx.x;
    const int e   = gid >> 3;
    const int sub = gid & 7;
    if (e >= E) return;

    const int i = e0[e];
    const int j = e1[e];

    const uint4 p = ((const uint4*)(pq + (size_t)i * 128))[sub];
    const uint4 q = ((const uint4*)(pq + (size_t)j * 128 + 64))[sub];

    const float4 w2a = ((const float4*)W2)[2 * sub];
    const float4 w2b = ((const float4*)W2)[2 * sub + 1];

    const u32 pw[4] = {p.x, p.y, p.z, p.w};
    const u32 qw[4] = {q.x, q.y, q.z, q.w};
    const float w2[8] = {w2a.x, w2a.y, w2a.z, w2a.w,
                         w2b.x, w2b.y, w2b.z, w2b.w};

    float part = 0.0f;
#pragma unroll
    for (int c = 0; c < 4; ++c) {
        float p0 = __uint_as_float(pw[c] << 16);
        float p1 = __uint_as_float(pw[c] & 0xffff0000u);
        float q0 = __uint_as_float(qw[c] << 16);
        float q1 = __uint_as_float(qw[c] & 0xffff0000u);
        float a0 = fmaxf(p0 + q0, 0.0f);
        float a1 = fmaxf(p1 + q1, 0.0f);
        part = fmaf(a0, w2[2 * c], part);
        part = fmaf(a1, w2[2 * c + 1], part);
    }

    part += __shfl_xor(part, 1);
    part += __shfl_xor(part, 2);
    part += __shfl_xor(part, 4);

    if (sub == 0) out[e] = part + b2[0];
}

// ---------------------------------------------------------------------------
extern "C" void kernel_launch(void* const* d_in, const int* in_sizes, int n_in,
                              void* d_out, int out_size, void* d_ws, size_t ws_size,
                              hipStream_t stream) {
    const float* z  = (const float*)d_in[0];
    const int*   eg = (const int*)d_in[1];
    const float* W1 = (const float*)d_in[2];
    const float* b1 = (const float*)d_in[3];
    const float* W2 = (const float*)d_in[4];
    const float* b2 = (const float*)d_in[5];
    float* out = (float*)d_out;

    const int nNodes = in_sizes[0] / 64;   // 100000
    const int E      = in_sizes[1] / 2;    // 1000000

    u16* pq = (u16*)d_ws;                  // nNodes*128*2 = 25.6 MB

    dim3 gA((nNodes + 63) / 64);           // 64 nodes per block
    node_precompute<<<gA, dim3(256), 0, stream>>>(z, W1, b1, pq, nNodes);

    // 8 threads per edge
    long long tB = (long long)E * 8;
    dim3 gB((unsigned)((tB + 255) / 256));
    edge_mlp<<<gB, dim3(256), 0, stream>>>(eg, eg + E, pq, W2, b2, out, E);
}

// Round 4
// 134.181 us; speedup vs baseline: 1.7985x; 1.6128x over previous
//
#include <hip/hip_runtime.h>
#include <hip/hip_bf16.h>

typedef unsigned short u16;
typedef unsigned int u32;
typedef __attribute__((ext_vector_type(8))) short bf16x8;   // 8 bf16 = 4 VGPR
typedef __attribute__((ext_vector_type(16))) float f32x16;  // 32x32 C/D frag

static __device__ __forceinline__ u16 f2bf(float f) {
    __hip_bfloat16 b = __float2bfloat16(f);   // RNE
    return *(u16*)&b;
}

// ---------------------------------------------------------------------------
// Kernel A (MFMA): pq[n][c] for c in 0..127, where
//   c <  64 (P): b1[c] + sum_k z[n][k] * W1[k][c]
//   c >= 64 (Q):         sum_k z[n][k] * W1[64+k][c-64]
// One wave = one 32-node tile x all 128 cols.
//   D(32n x 32c) = A(32n x 16k) . B(16k x 32c), K=64 -> 4 k-steps,
//   4 col-tiles -> 16 mfma_f32_32x32x16_bf16 per wave.
// B-frags (W1 as bf16) are built ONCE per wave into 64 VGPRs -> the per-k
// W1 load that killed R3 is gone. Kernel is memory-streaming (~51 MB).
// Layouts (guide-verified): A[m=lane&31][k=(lane>>5)*8+j], B[k][n=lane&31],
// D: col=lane&31, row=(reg&3)+8*(reg>>2)+4*(lane>>5).
// ---------------------------------------------------------------------------
__global__ __launch_bounds__(256) void node_mfma(
    const float* __restrict__ z, const float* __restrict__ W1,
    const float* __restrict__ b1, u16* __restrict__ pq, int nNodes)
{
    const int lane   = threadIdx.x & 63;
    const int wave   = threadIdx.x >> 6;
    const int l31    = lane & 31;
    const int half   = lane >> 5;
    const int nodeBase = (blockIdx.x * 4 + wave) * 32;
    if (nodeBase >= nNodes) return;

    // ---- B fragments: Bf[ct][ks], element j holds Wcat[ks*16+half*8+j][ct*32+l31]
    bf16x8 Bf[4][4];
#pragma unroll
    for (int ct = 0; ct < 4; ++ct) {
        const int c = ct * 32 + l31;                  // concat col 0..127
        const float* wc = (c < 64) ? (W1 + c) : (W1 + 64 * 64 + (c - 64));
#pragma unroll
        for (int ks = 0; ks < 4; ++ks) {
            const int kb = ks * 16 + half * 8;
#pragma unroll
            for (int j = 0; j < 8; ++j)
                Bf[ct][ks][j] = (short)f2bf(wc[(size_t)(kb + j) * 64]);
        }
    }

    // ---- A fragments: Af[ks], element j holds z[nodeBase+l31][ks*16+half*8+j]
    int zrowi = nodeBase + l31;
    if (zrowi > nNodes - 1) zrowi = nNodes - 1;       // clamp (safe redundant)
    const float* zrow = z + (size_t)zrowi * 64;
    bf16x8 Af[4];
#pragma unroll
    for (int ks = 0; ks < 4; ++ks) {
        const float4 v0 = *(const float4*)(zrow + ks * 16 + half * 8);
        const float4 v1 = *(const float4*)(zrow + ks * 16 + half * 8 + 4);
        Af[ks][0] = (short)f2bf(v0.x); Af[ks][1] = (short)f2bf(v0.y);
        Af[ks][2] = (short)f2bf(v0.z); Af[ks][3] = (short)f2bf(v0.w);
        Af[ks][4] = (short)f2bf(v1.x); Af[ks][5] = (short)f2bf(v1.y);
        Af[ks][6] = (short)f2bf(v1.z); Af[ks][7] = (short)f2bf(v1.w);
    }

    // ---- MFMA accumulate
    f32x16 acc[4];
#pragma unroll
    for (int ct = 0; ct < 4; ++ct) acc[ct] = (f32x16)(0.0f);
#pragma unroll
    for (int ks = 0; ks < 4; ++ks)
#pragma unroll
        for (int ct = 0; ct < 4; ++ct)
            acc[ct] = __builtin_amdgcn_mfma_f32_32x32x16_bf16(
                Af[ks], Bf[ct][ks], acc[ct], 0, 0, 0);

    // ---- epilogue: add b1 on P cols, pack bf16, store
#pragma unroll
    for (int ct = 0; ct < 4; ++ct) {
        const int c = ct * 32 + l31;
        const float bias = (c < 64) ? b1[c] : 0.0f;
#pragma unroll
        for (int reg = 0; reg < 16; ++reg) {
            const int r = (reg & 3) + 8 * (reg >> 2) + 4 * half; // node in tile
            const int node = nodeBase + r;
            if (node < nNodes)
                pq[(size_t)node * 128 + c] = f2bf(acc[ct][reg] + bias);
        }
    }
}

// ---------------------------------------------------------------------------
// Kernel B: edge MLP tail, 8 lanes per edge (unchanged from R3 so its
// counters surface cleanly this round).
//   out[e] = b2 + sum_h W2[h] * relu(P[i][h] + Q[j][h])
// ---------------------------------------------------------------------------
__global__ __launch_bounds__(256) void edge_mlp(
    const int* __restrict__ e0, const int* __restrict__ e1,
    const u16* __restrict__ pq, const float* __restrict__ W2,
    const float* __restrict__ b2, float* __restrict__ out, int E)
{
    const int gid = blockIdx.x * 256 + threadIdx.x;
    const int e   = gid >> 3;
    const int sub = gid & 7;
    if (e >= E) return;

    const int i = e0[e];
    const int j = e1[e];

    const uint4 p = ((const uint4*)(pq + (size_t)i * 128))[sub];
    const uint4 q = ((const uint4*)(pq + (size_t)j * 128 + 64))[sub];

    const float4 w2a = ((const float4*)W2)[2 * sub];
    const float4 w2b = ((const float4*)W2)[2 * sub + 1];

    const u32 pw[4] = {p.x, p.y, p.z, p.w};
    const u32 qw[4] = {q.x, q.y, q.z, q.w};
    const float w2[8] = {w2a.x, w2a.y, w2a.z, w2a.w,
                         w2b.x, w2b.y, w2b.z, w2b.w};

    float part = 0.0f;
#pragma unroll
    for (int c = 0; c < 4; ++c) {
        float p0 = __uint_as_float(pw[c] << 16);
        float p1 = __uint_as_float(pw[c] & 0xffff0000u);
        float q0 = __uint_as_float(qw[c] << 16);
        float q1 = __uint_as_float(qw[c] & 0xffff0000u);
        float a0 = fmaxf(p0 + q0, 0.0f);
        float a1 = fmaxf(p1 + q1, 0.0f);
        part = fmaf(a0, w2[2 * c], part);
        part = fmaf(a1, w2[2 * c + 1], part);
    }

    part += __shfl_xor(part, 1);
    part += __shfl_xor(part, 2);
    part += __shfl_xor(part, 4);

    if (sub == 0) out[e] = part + b2[0];
}

// ---------------------------------------------------------------------------
extern "C" void kernel_launch(void* const* d_in, const int* in_sizes, int n_in,
                              void* d_out, int out_size, void* d_ws, size_t ws_size,
                              hipStream_t stream) {
    const float* z  = (const float*)d_in[0];
    const int*   eg = (const int*)d_in[1];
    const float* W1 = (const float*)d_in[2];
    const float* b1 = (const float*)d_in[3];
    const float* W2 = (const float*)d_in[4];
    const float* b2 = (const float*)d_in[5];
    float* out = (float*)d_out;

    const int nNodes = in_sizes[0] / 64;   // 100000
    const int E      = in_sizes[1] / 2;    // 1000000

    u16* pq = (u16*)d_ws;                  // nNodes*128*2 = 25.6 MB

    dim3 gA((nNodes + 127) / 128);         // 4 waves x 32 nodes per block
    node_mfma<<<gA, dim3(256), 0, stream>>>(z, W1, b1, pq, nNodes);

    long long tB = (long long)E * 8;       // 8 threads per edge
    dim3 gB((unsigned)((tB + 255) / 256));
    edge_mlp<<<gB, dim3(256), 0, stream>>>(eg, eg + E, pq, W2, b2, out, E);
}

// Round 6
// 132.233 us; speedup vs baseline: 1.8250x; 1.0147x over previous
//
#include <hip/hip_runtime.h>
#include <hip/hip_bf16.h>

typedef unsigned short u16;
typedef unsigned int u32;
typedef __attribute__((ext_vector_type(8))) short bf16x8;   // 8 bf16 = 4 VGPR
typedef __attribute__((ext_vector_type(16))) float f32x16;  // 32x32 C/D frag
typedef _Float16 h16x2 __attribute__((ext_vector_type(2)));

static __device__ __forceinline__ u16 f2bf(float f) {
    __hip_bfloat16 b = __float2bfloat16(f);   // RNE
    return *(u16*)&b;
}
static __device__ __forceinline__ u16 f2h(float f) {
    _Float16 h = (_Float16)f;                  // RNE
    return __builtin_bit_cast(u16, h);
}

// ---------------------------------------------------------------------------
// Kernel A (MFMA): pq[n][c] for c in 0..127  (stored FP16), where
//   c <  64 (P): b1[c] + sum_k z[n][k] * W1[k][c]
//   c >= 64 (Q):         sum_k z[n][k] * W1[64+k][c-64]
// One wave = one 32-node tile x all 128 cols; 16 mfma_f32_32x32x16_bf16.
// B-frags (W1 as bf16) built once per wave -> no per-k W1 reload.
// Layouts (guide-verified): A[m=lane&31][k=(lane>>5)*8+j], B[k][n=lane&31],
// D: col=lane&31, row=(reg&3)+8*(reg>>2)+4*(lane>>5).
// ---------------------------------------------------------------------------
__global__ __launch_bounds__(256) void node_mfma(
    const float* __restrict__ z, const float* __restrict__ W1,
    const float* __restrict__ b1, u16* __restrict__ pq, int nNodes)
{
    const int lane   = threadIdx.x & 63;
    const int wave   = threadIdx.x >> 6;
    const int l31    = lane & 31;
    const int half   = lane >> 5;
    const int nodeBase = (blockIdx.x * 4 + wave) * 32;
    if (nodeBase >= nNodes) return;

    // ---- B fragments
    bf16x8 Bf[4][4];
#pragma unroll
    for (int ct = 0; ct < 4; ++ct) {
        const int c = ct * 32 + l31;                  // concat col 0..127
        const float* wc = (c < 64) ? (W1 + c) : (W1 + 64 * 64 + (c - 64));
#pragma unroll
        for (int ks = 0; ks < 4; ++ks) {
            const int kb = ks * 16 + half * 8;
#pragma unroll
            for (int j = 0; j < 8; ++j)
                Bf[ct][ks][j] = (short)f2bf(wc[(size_t)(kb + j) * 64]);
        }
    }

    // ---- A fragments
    int zrowi = nodeBase + l31;
    if (zrowi > nNodes - 1) zrowi = nNodes - 1;       // clamp (safe redundant)
    const float* zrow = z + (size_t)zrowi * 64;
    bf16x8 Af[4];
#pragma unroll
    for (int ks = 0; ks < 4; ++ks) {
        const float4 v0 = *(const float4*)(zrow + ks * 16 + half * 8);
        const float4 v1 = *(const float4*)(zrow + ks * 16 + half * 8 + 4);
        Af[ks][0] = (short)f2bf(v0.x); Af[ks][1] = (short)f2bf(v0.y);
        Af[ks][2] = (short)f2bf(v0.z); Af[ks][3] = (short)f2bf(v0.w);
        Af[ks][4] = (short)f2bf(v1.x); Af[ks][5] = (short)f2bf(v1.y);
        Af[ks][6] = (short)f2bf(v1.z); Af[ks][7] = (short)f2bf(v1.w);
    }

    // ---- MFMA accumulate
    f32x16 acc[4];
#pragma unroll
    for (int ct = 0; ct < 4; ++ct) acc[ct] = (f32x16)(0.0f);
#pragma unroll
    for (int ks = 0; ks < 4; ++ks)
#pragma unroll
        for (int ct = 0; ct < 4; ++ct)
            acc[ct] = __builtin_amdgcn_mfma_f32_32x32x16_bf16(
                Af[ks], Bf[ct][ks], acc[ct], 0, 0, 0);

    // ---- epilogue: add b1 on P cols, pack FP16, store
#pragma unroll
    for (int ct = 0; ct < 4; ++ct) {
        const int c = ct * 32 + l31;
        const float bias = (c < 64) ? b1[c] : 0.0f;
#pragma unroll
        for (int reg = 0; reg < 16; ++reg) {
            const int r = (reg & 3) + 8 * (reg >> 2) + 4 * half; // node in tile
            const int node = nodeBase + r;
            if (node < nNodes)
                pq[(size_t)node * 128 + c] = f2h(acc[ct][reg] + bias);
        }
    }
}

// ---------------------------------------------------------------------------
// Kernel B: edge MLP tail, 8 lanes per edge, packed fp16 math via native
// _Float16 vectors (avoids the __hadd2/__hmax2 bf16-overload ambiguity).
//   out[e] = b2 + sum_h W2[h] * relu(P[i][h] + Q[j][h])
// Inner loop per 2 h-terms: v_pk_add_f16 + v_pk_max_f16 + v_dot2_f32_f16.
// ---------------------------------------------------------------------------
__global__ __launch_bounds__(256) void edge_mlp(
    const int* __restrict__ e0, const int* __restrict__ e1,
    const u16* __restrict__ pq, const float* __restrict__ W2,
    const float* __restrict__ b2, float* __restrict__ out, int E)
{
    const int gid = blockIdx.x * 256 + threadIdx.x;
    const int e   = gid >> 3;
    const int sub = gid & 7;
    if (e >= E) return;

    const int i = e0[e];
    const int j = e1[e];

    const uint4 p = ((const uint4*)(pq + (size_t)i * 128))[sub];
    const uint4 q = ((const uint4*)(pq + (size_t)j * 128 + 64))[sub];

    const float4 wa = ((const float4*)W2)[2 * sub];
    const float4 wb = ((const float4*)W2)[2 * sub + 1];

    const u32 pw[4] = {p.x, p.y, p.z, p.w};
    const u32 qw[4] = {q.x, q.y, q.z, q.w};

    h16x2 w2h[4];
    w2h[0] = (h16x2){(_Float16)wa.x, (_Float16)wa.y};
    w2h[1] = (h16x2){(_Float16)wa.z, (_Float16)wa.w};
    w2h[2] = (h16x2){(_Float16)wb.x, (_Float16)wb.y};
    w2h[3] = (h16x2){(_Float16)wb.z, (_Float16)wb.w};
    const h16x2 hzero = (h16x2){(_Float16)0.0f, (_Float16)0.0f};

    float sum = 0.0f;
#pragma unroll
    for (int c = 0; c < 4; ++c) {
        h16x2 pp = __builtin_bit_cast(h16x2, pw[c]);
        h16x2 qq = __builtin_bit_cast(h16x2, qw[c]);
        h16x2 a  = __builtin_elementwise_max(pp + qq, hzero); // pk_add + pk_max
#if __has_builtin(__builtin_amdgcn_fdot2)
        sum = __builtin_amdgcn_fdot2(a, w2h[c], sum, false);
#else
        sum = fmaf((float)a[0], (float)w2h[c][0],
              fmaf((float)a[1], (float)w2h[c][1], sum));
#endif
    }

    sum += __shfl_xor(sum, 1);
    sum += __shfl_xor(sum, 2);
    sum += __shfl_xor(sum, 4);

    if (sub == 0) out[e] = sum + b2[0];
}

// ---------------------------------------------------------------------------
extern "C" void kernel_launch(void* const* d_in, const int* in_sizes, int n_in,
                              void* d_out, int out_size, void* d_ws, size_t ws_size,
                              hipStream_t stream) {
    const float* z  = (const float*)d_in[0];
    const int*   eg = (const int*)d_in[1];
    const float* W1 = (const float*)d_in[2];
    const float* b1 = (const float*)d_in[3];
    const float* W2 = (const float*)d_in[4];
    const float* b2 = (const float*)d_in[5];
    float* out = (float*)d_out;

    const int nNodes = in_sizes[0] / 64;   // 100000
    const int E      = in_sizes[1] / 2;    // 1000000

    u16* pq = (u16*)d_ws;                  // nNodes*128*2 = 25.6 MB (fp16)

    dim3 gA((nNodes + 127) / 128);         // 4 waves x 32 nodes per block
    node_mfma<<<gA, dim3(256), 0, stream>>>(z, W1, b1, pq, nNodes);

    long long tB = (long long)E * 8;       // 8 threads per edge
    dim3 gB((unsigned)((tB + 255) / 256));
    edge_mlp<<<gB, dim3(256), 0, stream>>>(eg, eg + E, pq, W2, b2, out, E);
}

// Round 7
// 123.201 us; speedup vs baseline: 1.9588x; 1.0733x over previous
//
#include <hip/hip_runtime.h>
#include <hip/hip_bf16.h>

typedef unsigned short u16;
typedef unsigned int u32;
typedef __attribute__((ext_vector_type(8))) short bf16x8;   // 8 bf16 = 4 VGPR
typedef __attribute__((ext_vector_type(16))) float f32x16;  // 32x32 C/D frag
typedef _Float16 h16x2 __attribute__((ext_vector_type(2)));

static __device__ __forceinline__ u16 f2bf(float f) {
    __hip_bfloat16 b = __float2bfloat16(f);   // RNE
    return *(u16*)&b;
}
static __device__ __forceinline__ u16 f2h(float f) {
    _Float16 h = (_Float16)f;                  // RNE
    return __builtin_bit_cast(u16, h);
}

// ---------------------------------------------------------------------------
// Kernel 0: build W1's MFMA B-fragment table ONCE (it is node-independent).
// wtab flat index = ((ct*4 + ks)*64 + lane)*8 + j  holds (bf16)
//   Wcat[k = ks*16 + (lane>>5)*8 + j][c = ct*32 + (lane&31)]
// where Wcat[k][c] = c<64 ? W1[k][c] : W1[64+k][c-64].
// 8192 elements = 16 KB. Writes perfectly coalesced; reads are 8192 one-off
// scattered L2 hits. This removes the per-wave 128-load L1-thrash that made
// node_mfma ~35 us in R4-R6.
// ---------------------------------------------------------------------------
__global__ __launch_bounds__(256) void build_wfrag(
    const float* __restrict__ W1, u16* __restrict__ wtab)
{
    const int flat = blockIdx.x * 256 + threadIdx.x;
    if (flat >= 8192) return;
    const int j    = flat & 7;
    const int lane = (flat >> 3) & 63;
    const int ks   = (flat >> 9) & 3;
    const int ct   = flat >> 11;
    const int k = ks * 16 + (lane >> 5) * 8 + j;
    const int c = ct * 32 + (lane & 31);
    const float v = (c < 64) ? W1[(size_t)k * 64 + c]
                             : W1[(size_t)(64 + k) * 64 + (c - 64)];
    wtab[flat] = f2bf(v);
}

// ---------------------------------------------------------------------------
// Kernel A (MFMA): pq[n][c] for c in 0..127 (stored FP16), where
//   c <  64 (P): b1[c] + sum_k z[n][k] * W1[k][c]
//   c >= 64 (Q):         sum_k z[n][k] * W1[64+k][c-64]
// One wave = one 32-node tile x all 128 cols; 16 mfma_f32_32x32x16_bf16.
// B-frags now come from wtab via 16 coalesced 16-B loads (L2-hot).
// Layouts (guide-verified): A[m=lane&31][k=(lane>>5)*8+j], B[k][n=lane&31],
// D: col=lane&31, row=(reg&3)+8*(reg>>2)+4*(lane>>5).
// ---------------------------------------------------------------------------
__global__ __launch_bounds__(256) void node_mfma(
    const float* __restrict__ z, const u16* __restrict__ wtab,
    const float* __restrict__ b1, u16* __restrict__ pq, int nNodes)
{
    const int lane   = threadIdx.x & 63;
    const int wave   = threadIdx.x >> 6;
    const int l31    = lane & 31;
    const int half   = lane >> 5;
    const int nodeBase = (blockIdx.x * 4 + wave) * 32;
    if (nodeBase >= nNodes) return;

    // ---- B fragments: coalesced loads from the precomputed table
    const bf16x8* wt = (const bf16x8*)wtab;
    bf16x8 Bf[4][4];
#pragma unroll
    for (int ct = 0; ct < 4; ++ct)
#pragma unroll
        for (int ks = 0; ks < 4; ++ks)
            Bf[ct][ks] = wt[(ct * 4 + ks) * 64 + lane];

    // ---- A fragments: Af[ks][j] = z[nodeBase+l31][ks*16 + half*8 + j]
    int zrowi = nodeBase + l31;
    if (zrowi > nNodes - 1) zrowi = nNodes - 1;       // clamp (safe redundant)
    const float* zrow = z + (size_t)zrowi * 64;
    bf16x8 Af[4];
#pragma unroll
    for (int ks = 0; ks < 4; ++ks) {
        const float4 v0 = *(const float4*)(zrow + ks * 16 + half * 8);
        const float4 v1 = *(const float4*)(zrow + ks * 16 + half * 8 + 4);
        Af[ks][0] = (short)f2bf(v0.x); Af[ks][1] = (short)f2bf(v0.y);
        Af[ks][2] = (short)f2bf(v0.z); Af[ks][3] = (short)f2bf(v0.w);
        Af[ks][4] = (short)f2bf(v1.x); Af[ks][5] = (short)f2bf(v1.y);
        Af[ks][6] = (short)f2bf(v1.z); Af[ks][7] = (short)f2bf(v1.w);
    }

    // ---- MFMA accumulate
    f32x16 acc[4];
#pragma unroll
    for (int ct = 0; ct < 4; ++ct) acc[ct] = (f32x16)(0.0f);
#pragma unroll
    for (int ks = 0; ks < 4; ++ks)
#pragma unroll
        for (int ct = 0; ct < 4; ++ct)
            acc[ct] = __builtin_amdgcn_mfma_f32_32x32x16_bf16(
                Af[ks], Bf[ct][ks], acc[ct], 0, 0, 0);

    // ---- epilogue: add b1 on P cols, pack FP16, store
#pragma unroll
    for (int ct = 0; ct < 4; ++ct) {
        const int c = ct * 32 + l31;
        const float bias = (c < 64) ? b1[c] : 0.0f;
#pragma unroll
        for (int reg = 0; reg < 16; ++reg) {
            const int r = (reg & 3) + 8 * (reg >> 2) + 4 * half; // node in tile
            const int node = nodeBase + r;
            if (node < nNodes)
                pq[(size_t)node * 128 + c] = f2h(acc[ct][reg] + bias);
        }
    }
}

// ---------------------------------------------------------------------------
// Kernel B: edge MLP tail, 8 lanes per edge, packed fp16 math (unchanged —
// shown gather-bound in R6; VALU trim bought only ~2 us).
//   out[e] = b2 + sum_h W2[h] * relu(P[i][h] + Q[j][h])
// ---------------------------------------------------------------------------
__global__ __launch_bounds__(256) void edge_mlp(
    const int* __restrict__ e0, const int* __restrict__ e1,
    const u16* __restrict__ pq, const float* __restrict__ W2,
    const float* __restrict__ b2, float* __restrict__ out, int E)
{
    const int gid = blockIdx.x * 256 + threadIdx.x;
    const int e   = gid >> 3;
    const int sub = gid & 7;
    if (e >= E) return;

    const int i = e0[e];
    const int j = e1[e];

    const uint4 p = ((const uint4*)(pq + (size_t)i * 128))[sub];
    const uint4 q = ((const uint4*)(pq + (size_t)j * 128 + 64))[sub];

    const float4 wa = ((const float4*)W2)[2 * sub];
    const float4 wb = ((const float4*)W2)[2 * sub + 1];

    const u32 pw[4] = {p.x, p.y, p.z, p.w};
    const u32 qw[4] = {q.x, q.y, q.z, q.w};

    h16x2 w2h[4];
    w2h[0] = (h16x2){(_Float16)wa.x, (_Float16)wa.y};
    w2h[1] = (h16x2){(_Float16)wa.z, (_Float16)wa.w};
    w2h[2] = (h16x2){(_Float16)wb.x, (_Float16)wb.y};
    w2h[3] = (h16x2){(_Float16)wb.z, (_Float16)wb.w};
    const h16x2 hzero = (h16x2){(_Float16)0.0f, (_Float16)0.0f};

    float sum = 0.0f;
#pragma unroll
    for (int c = 0; c < 4; ++c) {
        h16x2 pp = __builtin_bit_cast(h16x2, pw[c]);
        h16x2 qq = __builtin_bit_cast(h16x2, qw[c]);
        h16x2 a  = __builtin_elementwise_max(pp + qq, hzero); // pk_add + pk_max
#if __has_builtin(__builtin_amdgcn_fdot2)
        sum = __builtin_amdgcn_fdot2(a, w2h[c], sum, false);
#else
        sum = fmaf((float)a[0], (float)w2h[c][0],
              fmaf((float)a[1], (float)w2h[c][1], sum));
#endif
    }

    sum += __shfl_xor(sum, 1);
    sum += __shfl_xor(sum, 2);
    sum += __shfl_xor(sum, 4);

    if (sub == 0) out[e] = sum + b2[0];
}

// ---------------------------------------------------------------------------
extern "C" void kernel_launch(void* const* d_in, const int* in_sizes, int n_in,
                              void* d_out, int out_size, void* d_ws, size_t ws_size,
                              hipStream_t stream) {
    const float* z  = (const float*)d_in[0];
    const int*   eg = (const int*)d_in[1];
    const float* W1 = (const float*)d_in[2];
    const float* b1 = (const float*)d_in[3];
    const float* W2 = (const float*)d_in[4];
    const float* b2 = (const float*)d_in[5];
    float* out = (float*)d_out;

    const int nNodes = in_sizes[0] / 64;   // 100000
    const int E      = in_sizes[1] / 2;    // 1000000

    u16* wtab = (u16*)d_ws;                        // 16 KB fragment table
    u16* pq   = (u16*)d_ws + 16384;                // nNodes*128*2 = 25.6 MB

    build_wfrag<<<dim3(32), dim3(256), 0, stream>>>(W1, wtab);

    dim3 gA((nNodes + 127) / 128);         // 4 waves x 32 nodes per block
    node_mfma<<<gA, dim3(256), 0, stream>>>(z, wtab, b1, pq, nNodes);

    long long tB = (long long)E * 8;       // 8 threads per edge
    dim3 gB((unsigned)((tB + 255) / 256));
    edge_mlp<<<gB, dim3(256), 0, stream>>>(eg, eg + E, pq, W2, b2, out, E);
}